// Round 1
// baseline (587.872 us; speedup 1.0000x reference)
//
#include <hip/hip_runtime.h>

// ---------------------------------------------------------------------------
// TpMLPBlock on MI355X.
// Pipeline:
//  k_prep: convert full_w / pin^T to bf16, zero qsum
//  k0   : x fp32 -> xb bf16, per-parity channel sums (for mean of MixC)
//  k1   : MFMA GEMM xb @ [pin_h|pin_w]  -> p (bf16, window layouts)
//  k2   : MFMA GEMM per-head window mixing -> q scattered into A_ext cols 512..543,
//         + qsum (spatial mean of q per batch) via atomics
//  k3a  : mean assembly -> reweight MLP -> softmax a0/a1/a2; bias_vec
//  k3b  : per-batch B^T = [proj_w ; (pout_h.a0)@proj_w ; (pout_w.a1)@proj_w] bf16
//  k4   : v = MixC(x)*a2 -> A_ext cols 0..511 (bf16)
//  k5   : MFMA GEMM  out[65536,512] = A_ext[65536,544] @ B^T[b] + bias_vec[b]
// ---------------------------------------------------------------------------

typedef short bf16x8 __attribute__((ext_vector_type(8)));
typedef float f32x4 __attribute__((ext_vector_type(4)));

__device__ __forceinline__ unsigned short f2bf(float f) {
  union { float f; unsigned u; } v; v.f = f;
  unsigned r = v.u + 0x7fffu + ((v.u >> 16) & 1u);
  return (unsigned short)(r >> 16);
}
__device__ __forceinline__ float bf2f(unsigned short h) {
  union { unsigned u; float f; } v; v.u = ((unsigned)h) << 16;
  return v.f;
}
__device__ __forceinline__ void gload16(const void* g, void* l) {
  __builtin_amdgcn_global_load_lds(
      (const __attribute__((address_space(1))) unsigned int*)g,
      (__attribute__((address_space(3))) unsigned int*)l, 16, 0, 0);
}

// ---------------- k_prep: small weight conversions + qsum zero -------------
__global__ __launch_bounds__(256) void k_prep(
    const float* __restrict__ mhfw, const float* __restrict__ mwfw,
    const float* __restrict__ mhpin, const float* __restrict__ mwpin,
    unsigned short* __restrict__ wfull, unsigned short* __restrict__ pin_bt,
    float* __restrict__ qsum) {
  int tid = blockIdx.x * 256 + threadIdx.x;
  int stride = gridDim.x * 256;
  for (int i = tid; i < 2 * 128 * 1024; i += stride) {
    int which = i >> 17, idx = i & 131071;
    wfull[i] = f2bf(which ? mwfw[idx] : mhfw[idx]);
  }
  for (int i = tid; i < 32 * 512; i += stride) {
    int n = i >> 9, k = i & 511;
    float v = (n < 16) ? mhpin[k * 16 + n] : mwpin[k * 16 + (n - 16)];
    pin_bt[i] = f2bf(v);
  }
  for (int i = tid; i < 512; i += stride) qsum[i] = 0.f;
}

// ---------------- k0: x -> bf16 + parity partial sums ----------------------
__global__ __launch_bounds__(256) void k0(const float* __restrict__ x,
                                          unsigned short* __restrict__ xb,
                                          float* __restrict__ part) {
  __shared__ float lds[2048];
  int blk = blockIdx.x;  // 256 blocks x 256 tokens
  int tid = threadIdx.x;
  int cq = tid & 127, rp = tid >> 7;
  int ch0 = cq * 4;
  size_t t0 = (size_t)blk * 256;
  float acc[2][4] = {};
#pragma unroll 4
  for (int it = 0; it < 128; ++it) {
    int tl = rp + 2 * it;
    size_t off = (t0 + tl) * 512 + ch0;
    float4 v = *(const float4*)&x[off];
    int dy = (tl >> 6) & 1;
    acc[dy][0] += v.x; acc[dy][1] += v.y; acc[dy][2] += v.z; acc[dy][3] += v.w;
    uint2 u;
    u.x = (unsigned)f2bf(v.x) | ((unsigned)f2bf(v.y) << 16);
    u.y = (unsigned)f2bf(v.z) | ((unsigned)f2bf(v.w) << 16);
    *(uint2*)&xb[off] = u;
  }
  for (int dy = 0; dy < 2; ++dy) {
    int d = dy * 2 + rp;  // (y parity)*2 + (x parity)
    for (int j = 0; j < 4; ++j) lds[d * 512 + ch0 + j] = acc[dy][j];
  }
  __syncthreads();
  for (int i = tid; i < 2048; i += 256) part[(size_t)blk * 2048 + i] = lds[i];
}

// ---------------- k1: proj_in GEMM [65536,512]@[512,32] --------------------
__global__ __launch_bounds__(256) void k1(
    const unsigned short* __restrict__ xb, const unsigned short* __restrict__ pin_bt,
    const float* __restrict__ mh_pin_b, const float* __restrict__ mw_pin_b,
    unsigned short* __restrict__ p_bf) {
  __shared__ unsigned short As[128 * 64];
  __shared__ unsigned short Bs[32 * 64];
  int mt = blockIdx.x;  // 512
  int tid = threadIdx.x, w = tid >> 6, l = tid & 63;
  int sr = l >> 3, sc = l & 7;
  f32x4 acc[2][2] = {};
  for (int kc = 0; kc < 8; ++kc) {  // K chunks of 64
#pragma unroll
    for (int c2 = 0; c2 < 4; ++c2) {
      int call = w * 4 + c2;
      int row = call * 8 + sr;
      gload16(xb + (size_t)(mt * 128 + row) * 512 + kc * 64 + sc * 8, &As[call * 512]);
    }
    {
      int row = w * 8 + sr;
      gload16(pin_bt + (size_t)row * 512 + kc * 64 + sc * 8, &Bs[w * 512]);
    }
    __syncthreads();
    bf16x8 af[2][2], bq[2][2];
#pragma unroll
    for (int fr = 0; fr < 2; ++fr) {
      int row = w * 32 + fr * 16 + (l & 15);
#pragma unroll
      for (int ks = 0; ks < 2; ++ks)
        af[fr][ks] = *(const bf16x8*)&As[row * 64 + ks * 32 + (l >> 4) * 8];
    }
#pragma unroll
    for (int fc = 0; fc < 2; ++fc) {
      int col = fc * 16 + (l & 15);
#pragma unroll
      for (int ks = 0; ks < 2; ++ks)
        bq[fc][ks] = *(const bf16x8*)&Bs[col * 64 + ks * 32 + (l >> 4) * 8];
    }
#pragma unroll
    for (int ks = 0; ks < 2; ++ks)
#pragma unroll
      for (int fr = 0; fr < 2; ++fr)
#pragma unroll
        for (int fc = 0; fc < 2; ++fc)
          acc[fr][fc] = __builtin_amdgcn_mfma_f32_16x16x32_bf16(
              af[fr][ks], bq[fc][ks], acc[fr][fc], 0, 0, 0);
    __syncthreads();
  }
  // epilogue: scatter p into window layouts (bf16)
#pragma unroll
  for (int fc = 0; fc < 2; ++fc) {
    int col = fc * 16 + (l & 15);
    float pb = (col < 16) ? mh_pin_b[col] : mw_pin_b[col - 16];
    int dd = col & 1;
    int whichm = (col < 16) ? (col >> 1) : (8 + ((col - 16) >> 1));
#pragma unroll
    for (int fr = 0; fr < 2; ++fr)
#pragma unroll
      for (int r = 0; r < 4; ++r) {
        int t = mt * 128 + w * 32 + fr * 16 + (l >> 4) * 4 + r;
        float val = acc[fr][fc][r] + pb;
        int bb = t >> 12, y = (t >> 6) & 63, xc = t & 63;
        int n1 = y & 1, ii = y >> 1, n2 = xc & 1, jj = xc >> 1;
        int b4 = bb * 4 + n1 * 2 + n2;
        int win, f;
        if (col < 16) { win = b4 * 16 + (jj >> 1); f = ii * 4 + (jj & 1) * 2 + dd; }
        else          { win = b4 * 16 + (ii >> 1); f = (ii & 1) * 64 + jj * 2 + dd; }
        p_bf[((size_t)whichm * 1024 + win) * 128 + f] = f2bf(val);
      }
  }
}

// ---------------- k2: per-head window mixing GEMM --------------------------
__global__ __launch_bounds__(256) void k2(
    const unsigned short* __restrict__ p_bf, const unsigned short* __restrict__ wfull,
    const float* __restrict__ mh_full_b, const float* __restrict__ mw_full_b,
    unsigned short* __restrict__ A_ext, float* __restrict__ qsum) {
  __shared__ unsigned short As[128 * 32];
  __shared__ unsigned short Bs[128 * 32];
  int bid = blockIdx.x;  // 128 = 2 which * 8 m * 8 mt
  int which = bid >> 6, m = (bid >> 3) & 7, mt = bid & 7;
  int tid = threadIdx.x, w = tid >> 6, l = tid & 63;
  int wr = w >> 1, wc = w & 1;
  const unsigned short* A = p_bf + (size_t)(which * 8 + m) * 131072;
  const unsigned short* BTw = wfull + (size_t)which * 131072 + m * 128;
  int win0 = mt * 128;
  f32x4 acc[4][4] = {};
  int sr = l >> 2, sc = l & 3;
  for (int kc = 0; kc < 4; ++kc) {
#pragma unroll
    for (int c2 = 0; c2 < 2; ++c2) {
      int call = w * 2 + c2;
      int row = call * 16 + sr;
      gload16(A + (size_t)(win0 + row) * 128 + kc * 32 + sc * 8, &As[call * 512]);
      gload16(BTw + (size_t)row * 1024 + kc * 32 + sc * 8, &Bs[call * 512]);
    }
    __syncthreads();
    bf16x8 af[4], bq[4];
#pragma unroll
    for (int fr = 0; fr < 4; ++fr)
      af[fr] = *(const bf16x8*)&As[(wr * 64 + fr * 16 + (l & 15)) * 32 + (l >> 4) * 8];
#pragma unroll
    for (int fc = 0; fc < 4; ++fc)
      bq[fc] = *(const bf16x8*)&Bs[(wc * 64 + fc * 16 + (l & 15)) * 32 + (l >> 4) * 8];
#pragma unroll
    for (int fr = 0; fr < 4; ++fr)
#pragma unroll
      for (int fc = 0; fc < 4; ++fc)
        acc[fr][fc] = __builtin_amdgcn_mfma_f32_16x16x32_bf16(af[fr], bq[fc], acc[fr][fc], 0, 0, 0);
    __syncthreads();
  }
  const float* fbp = which ? mw_full_b : mh_full_b;
  float psum = 0.f;
#pragma unroll
  for (int fc = 0; fc < 4; ++fc) {
    int f = wc * 64 + fc * 16 + (l & 15);
    float fb = fbp[f];
    int dd = f & 1;
#pragma unroll
    for (int fr = 0; fr < 4; ++fr)
#pragma unroll
      for (int r = 0; r < 4; ++r) {
        int win = win0 + wr * 64 + fr * 16 + (l >> 4) * 4 + r;
        float q = acc[fr][fc][r] + fb;
        psum += q;
        int b4 = win >> 4, loc = win & 15;
        int n1 = (b4 >> 1) & 1, n2 = b4 & 1, bb = b4 >> 2;
        int i_, j_;
        if (which == 0) { i_ = f >> 2;              j_ = loc * 2 + ((f >> 1) & 1); }
        else            { i_ = loc * 2 + (f >> 6);  j_ = (f >> 1) & 31; }
        int y = i_ * 2 + n1, xc = j_ * 2 + n2;
        size_t t = (size_t)bb * 4096 + y * 64 + xc;
        A_ext[t * 544 + 512 + which * 16 + m * 2 + dd] = f2bf(q);
      }
  }
  for (int off = 2; off < 64; off <<= 1) psum += __shfl_xor(psum, off);
  if (l < 2) atomicAdd(&qsum[(mt * 2 + wr) * 32 + which * 16 + m * 2 + l], psum);
}

// ---------------- k3a: mean assembly + reweight MLP + softmax --------------
__global__ __launch_bounds__(256) void k3a(
    const float* __restrict__ part, const float* __restrict__ qsum,
    const float* __restrict__ cw, const float* __restrict__ cb,
    const float* __restrict__ mh_pout_w, const float* __restrict__ mh_pout_b,
    const float* __restrict__ mw_pout_w, const float* __restrict__ mw_pout_b,
    const float* __restrict__ fc1w, const float* __restrict__ fc1b,
    const float* __restrict__ fc2w, const float* __restrict__ fc2b,
    const float* __restrict__ proj_w, const float* __restrict__ proj_b,
    float* __restrict__ a_w, float* __restrict__ bias_vec) {
  __shared__ float apre[512], zz[128], a0s[512], a1s[512];
  int b = blockIdx.x, tid = threadIdx.x;
  float qh[16], qw[16];
#pragma unroll
  for (int k = 0; k < 16; ++k) {
    qh[k] = qsum[b * 32 + k] * (1.f / 4096.f);
    qw[k] = qsum[b * 32 + 16 + k] * (1.f / 4096.f);
  }
  for (int ch = tid; ch < 512; ch += 256) {
    float sd[4] = {0.f, 0.f, 0.f, 0.f};
    for (int i = 0; i < 16; ++i) {
      const float* pp = part + (size_t)(b * 16 + i) * 2048 + ch;
      sd[0] += pp[0]; sd[1] += pp[512]; sd[2] += pp[1024]; sd[3] += pp[1536];
    }
    float mc = 0.f;
#pragma unroll
    for (int d = 0; d < 4; ++d) {
      float wsum = cw[ch * 16 + d * 4] + cw[ch * 16 + d * 4 + 1] +
                   cw[ch * 16 + d * 4 + 2] + cw[ch * 16 + d * 4 + 3];
      mc += sd[d] * wsum;
    }
    mc *= (1.f / 4096.f);
    mc += 0.25f * (cb[ch * 4] + cb[ch * 4 + 1] + cb[ch * 4 + 2] + cb[ch * 4 + 3]);
    float v = mc + mh_pout_b[ch] + mw_pout_b[ch];
#pragma unroll
    for (int k = 0; k < 16; ++k)
      v += qh[k] * mh_pout_w[k * 512 + ch] + qw[k] * mw_pout_w[k * 512 + ch];
    apre[ch] = v;
  }
  __syncthreads();
  if (tid < 128) {
    float s = fc1b[tid];
    for (int c = 0; c < 512; ++c) s += apre[c] * fc1w[c * 128 + tid];
    zz[tid] = 0.5f * s * (1.f + erff(s * 0.70710678118654752f));
  }
  __syncthreads();
  for (int ch = tid; ch < 512; ch += 256) {
    float l0 = fc2b[ch * 3], l1 = fc2b[ch * 3 + 1], l2 = fc2b[ch * 3 + 2];
    for (int j = 0; j < 128; ++j) {
      float z = zz[j];
      l0 += z * fc2w[j * 1536 + ch * 3];
      l1 += z * fc2w[j * 1536 + ch * 3 + 1];
      l2 += z * fc2w[j * 1536 + ch * 3 + 2];
    }
    float mx = fmaxf(l0, fmaxf(l1, l2));
    float e0 = expf(l0 - mx), e1 = expf(l1 - mx), e2 = expf(l2 - mx);
    float inv = 1.f / (e0 + e1 + e2);
    float A0 = e0 * inv, A1 = e1 * inv, A2 = e2 * inv;
    a0s[ch] = A0; a1s[ch] = A1;
    a_w[b * 512 + ch] = A0;
    a_w[8192 + b * 512 + ch] = A1;
    a_w[16384 + b * 512 + ch] = A2;
  }
  __syncthreads();
  // coef[c] = pout_b_h[c]*a0 + pout_b_w[c]*a1  (reuse apre)
  for (int ch = tid; ch < 512; ch += 256)
    apre[ch] = mh_pout_b[ch] * a0s[ch] + mw_pout_b[ch] * a1s[ch];
  __syncthreads();
  for (int n = tid; n < 512; n += 256) {
    float bv = proj_b[n];
    for (int c = 0; c < 512; ++c) bv += apre[c] * proj_w[(size_t)c * 512 + n];
    bias_vec[b * 512 + n] = bv;
  }
}

// ---------------- k3b: per-batch B^T construction --------------------------
__global__ __launch_bounds__(256) void k3b(
    const float* __restrict__ a_w, const float* __restrict__ proj_w,
    const float* __restrict__ mh_pout_w, const float* __restrict__ mw_pout_w,
    unsigned short* __restrict__ BT) {
  int b = blockIdx.x >> 3, nc = blockIdx.x & 7;
  int tid = threadIdx.x;
  __shared__ float a0s[512], a1s[512];
  for (int c = tid; c < 512; c += 256) {
    a0s[c] = a_w[b * 512 + c];
    a1s[c] = a_w[8192 + b * 512 + c];
  }
  __syncthreads();
  // rows k<512 : proj_w^T (bf16)
  for (int i8 = tid; i8 < 4096; i8 += 256) {
    int nl = i8 >> 6, k0 = (i8 & 63) * 8;
    int n = nc * 64 + nl;
    unsigned p0 = (unsigned)f2bf(proj_w[(size_t)(k0 + 0) * 512 + n]) |
                  ((unsigned)f2bf(proj_w[(size_t)(k0 + 1) * 512 + n]) << 16);
    unsigned p1 = (unsigned)f2bf(proj_w[(size_t)(k0 + 2) * 512 + n]) |
                  ((unsigned)f2bf(proj_w[(size_t)(k0 + 3) * 512 + n]) << 16);
    unsigned p2 = (unsigned)f2bf(proj_w[(size_t)(k0 + 4) * 512 + n]) |
                  ((unsigned)f2bf(proj_w[(size_t)(k0 + 5) * 512 + n]) << 16);
    unsigned p3 = (unsigned)f2bf(proj_w[(size_t)(k0 + 6) * 512 + n]) |
                  ((unsigned)f2bf(proj_w[(size_t)(k0 + 7) * 512 + n]) << 16);
    uint4 u; u.x = p0; u.y = p1; u.z = p2; u.w = p3;
    *(uint4*)&BT[((size_t)(b * 512 + n)) * 544 + k0] = u;
  }
  // rows 512..543 : A_h / A_w
  for (int idx = tid; idx < 1024; idx += 256) {
    int md = idx >> 6, nl = idx & 63;
    int n = nc * 64 + nl;
    float s0 = 0.f, s1 = 0.f;
    for (int c = 0; c < 512; ++c) {
      float pw = proj_w[(size_t)c * 512 + n];
      s0 += mh_pout_w[md * 512 + c] * a0s[c] * pw;
      s1 += mw_pout_w[md * 512 + c] * a1s[c] * pw;
    }
    BT[((size_t)(b * 512 + n)) * 544 + 512 + md] = f2bf(s0);
    BT[((size_t)(b * 512 + n)) * 544 + 528 + md] = f2bf(s1);
  }
}

// ---------------- k4: v = MixC(x) * a2 -> A_ext cols 0..511 ----------------
__global__ __launch_bounds__(256) void k4(const unsigned short* __restrict__ xb,
                                          const float* __restrict__ cw,
                                          const float* __restrict__ cb,
                                          const float* __restrict__ a_w,
                                          unsigned short* __restrict__ A_ext) {
  int blk = blockIdx.x;  // 512: 2 rows each
  int b = blk >> 5, y0 = (blk & 31) * 2;
  int tid = threadIdx.x;
  int ch0 = tid * 2;
  float wreg[2][16], breg[2][4], a2v[2];
#pragma unroll
  for (int cc = 0; cc < 2; ++cc) {
    int ch = ch0 + cc;
#pragma unroll
    for (int i = 0; i < 16; ++i) wreg[cc][i] = cw[ch * 16 + i];
#pragma unroll
    for (int i = 0; i < 4; ++i) breg[cc][i] = cb[ch * 4 + i];
    a2v[cc] = a_w[16384 + b * 512 + ch];
  }
  size_t rbase = ((size_t)b * 4096 + (size_t)y0 * 64) * 512;
  for (int j = 0; j < 32; ++j) {
    unsigned xw[4];
    xw[0] = *(const unsigned*)&xb[rbase + (size_t)(2 * j) * 512 + ch0];
    xw[1] = *(const unsigned*)&xb[rbase + (size_t)(2 * j + 1) * 512 + ch0];
    xw[2] = *(const unsigned*)&xb[rbase + 32768 + (size_t)(2 * j) * 512 + ch0];
    xw[3] = *(const unsigned*)&xb[rbase + 32768 + (size_t)(2 * j + 1) * 512 + ch0];
    float xv[4][2];
#pragma unroll
    for (int d = 0; d < 4; ++d) {
      xv[d][0] = bf2f((unsigned short)(xw[d] & 0xffffu));
      xv[d][1] = bf2f((unsigned short)(xw[d] >> 16));
    }
#pragma unroll
    for (int dh = 0; dh < 2; ++dh)
#pragma unroll
      for (int dw = 0; dw < 2; ++dw) {
        int Dp = dh * 2 + dw;
        unsigned short o2[2];
#pragma unroll
        for (int cc = 0; cc < 2; ++cc) {
          float v = breg[cc][Dp];
#pragma unroll
          for (int d = 0; d < 4; ++d) v += xv[d][cc] * wreg[cc][d * 4 + Dp];
          o2[cc] = f2bf(v * a2v[cc]);
        }
        size_t t = (size_t)b * 4096 + (size_t)(y0 + dh) * 64 + (2 * j + dw);
        *(unsigned*)&A_ext[t * 544 + ch0] = (unsigned)o2[0] | ((unsigned)o2[1] << 16);
      }
  }
}

// ---------------- k5: final GEMM [65536,544]@[544,512] + bias --------------
__global__ __launch_bounds__(256) void k5(const unsigned short* __restrict__ A_ext,
                                          const unsigned short* __restrict__ BT_all,
                                          const float* __restrict__ bias_vec,
                                          float* __restrict__ out) {
  __shared__ unsigned short As[128 * 32];
  __shared__ unsigned short Bs[128 * 32];
  int bid = blockIdx.x;
  int mt = bid >> 2, nt = bid & 3;
  int b = mt >> 5;
  int tid = threadIdx.x, w = tid >> 6, l = tid & 63;
  int wr = w >> 1, wc = w & 1;
  const unsigned short* Abase = A_ext + (size_t)(mt * 128) * 544;
  const unsigned short* Bbase = BT_all + ((size_t)(b * 512 + nt * 128)) * 544;
  f32x4 acc[4][4] = {};
  int sr = l >> 2, sc = l & 3;
  for (int kc = 0; kc < 17; ++kc) {
#pragma unroll
    for (int c2 = 0; c2 < 2; ++c2) {
      int call = w * 2 + c2;
      int row = call * 16 + sr;
      gload16(Abase + (size_t)row * 544 + kc * 32 + sc * 8, &As[call * 512]);
      gload16(Bbase + (size_t)row * 544 + kc * 32 + sc * 8, &Bs[call * 512]);
    }
    __syncthreads();
    bf16x8 af[4], bq[4];
#pragma unroll
    for (int fr = 0; fr < 4; ++fr)
      af[fr] = *(const bf16x8*)&As[(wr * 64 + fr * 16 + (l & 15)) * 32 + (l >> 4) * 8];
#pragma unroll
    for (int fc = 0; fc < 4; ++fc)
      bq[fc] = *(const bf16x8*)&Bs[(wc * 64 + fc * 16 + (l & 15)) * 32 + (l >> 4) * 8];
#pragma unroll
    for (int fr = 0; fr < 4; ++fr)
#pragma unroll
      for (int fc = 0; fc < 4; ++fc)
        acc[fr][fc] = __builtin_amdgcn_mfma_f32_16x16x32_bf16(af[fr], bq[fc], acc[fr][fc], 0, 0, 0);
    __syncthreads();
  }
  float bvals[4];
#pragma unroll
  for (int fc = 0; fc < 4; ++fc)
    bvals[fc] = bias_vec[b * 512 + nt * 128 + wc * 64 + fc * 16 + (l & 15)];
#pragma unroll
  for (int fr = 0; fr < 4; ++fr) {
    int row = mt * 128 + wr * 64 + fr * 16 + (l >> 4) * 4;
#pragma unroll
    for (int r = 0; r < 4; ++r) {
      size_t obase = (size_t)(row + r) * 512 + nt * 128 + wc * 64 + (l & 15);
#pragma unroll
      for (int fc = 0; fc < 4; ++fc) out[obase + fc * 16] = acc[fr][fc][r] + bvals[fc];
    }
  }
}

// ---------------------------------------------------------------------------
extern "C" void kernel_launch(void* const* d_in, const int* in_sizes, int n_in,
                              void* d_out, int out_size, void* d_ws, size_t ws_size,
                              hipStream_t stream) {
  const float* x         = (const float*)d_in[0];
  const float* mh_pin_w  = (const float*)d_in[1];
  const float* mh_pin_b  = (const float*)d_in[2];
  const float* mh_full_w = (const float*)d_in[3];
  const float* mh_full_b = (const float*)d_in[4];
  const float* mh_pout_w = (const float*)d_in[5];
  const float* mh_pout_b = (const float*)d_in[6];
  const float* mw_pin_w  = (const float*)d_in[7];
  const float* mw_pin_b  = (const float*)d_in[8];
  const float* mw_full_w = (const float*)d_in[9];
  const float* mw_full_b = (const float*)d_in[10];
  const float* mw_pout_w = (const float*)d_in[11];
  const float* mw_pout_b = (const float*)d_in[12];
  const float* cw        = (const float*)d_in[13];
  const float* cb        = (const float*)d_in[14];
  const float* fc1w      = (const float*)d_in[15];
  const float* fc1b      = (const float*)d_in[16];
  const float* fc2w      = (const float*)d_in[17];
  const float* fc2b      = (const float*)d_in[18];
  const float* proj_w    = (const float*)d_in[19];
  const float* proj_b    = (const float*)d_in[20];
  float* out = (float*)d_out;

  char* ws = (char*)d_ws;
  unsigned short* A_ext  = (unsigned short*)(ws + 0);            // 65536*544*2
  unsigned short* xb     = (unsigned short*)(ws + 71303168);     // 65536*512*2
  unsigned short* BT_all = (unsigned short*)(ws + 138412032);    // 16*512*544*2
  unsigned short* p_bf   = (unsigned short*)(ws + 147324928);    // 16*1024*128*2
  unsigned short* wfull  = (unsigned short*)(ws + 151519232);    // 2*128*1024*2
  unsigned short* pin_bt = (unsigned short*)(ws + 152043520);    // 32*512*2
  float* part    = (float*)(ws + 152076288);                     // 256*2048*4
  float* qsum    = (float*)(ws + 154173440);                     // 512*4
  float* a_wv    = (float*)(ws + 154175488);                     // 3*16*512*4
  float* bias_v  = (float*)(ws + 154273792);                     // 16*512*4

  k_prep<<<128, 256, 0, stream>>>(mh_full_w, mw_full_w, mh_pin_w, mw_pin_w, wfull, pin_bt, qsum);
  k0<<<256, 256, 0, stream>>>(x, xb, part);
  k1<<<512, 256, 0, stream>>>(xb, pin_bt, mh_pin_b, mw_pin_b, p_bf);
  k2<<<128, 256, 0, stream>>>(p_bf, wfull, mh_full_b, mw_full_b, A_ext, qsum);
  k3a<<<16, 256, 0, stream>>>(part, qsum, cw, cb, mh_pout_w, mh_pout_b, mw_pout_w, mw_pout_b,
                              fc1w, fc1b, fc2w, fc2b, proj_w, proj_b, a_wv, bias_v);
  k3b<<<128, 256, 0, stream>>>(a_wv, proj_w, mh_pout_w, mw_pout_w, BT_all);
  k4<<<512, 256, 0, stream>>>(xb, cw, cb, a_wv, A_ext);
  k5<<<2048, 256, 0, stream>>>(A_ext, BT_all, bias_v, out);
}

// Round 6
// 538.657 us; speedup vs baseline: 1.0914x; 1.0914x over previous
//
#include <hip/hip_runtime.h>

// ---------------------------------------------------------------------------
// TpMLPBlock on MI355X.
//  k_prep: convert full_w / pin^T to bf16, zero qsum
//  kT   : proj_w -> projT bf16 [n][k] (LDS transpose, shared across batch)
//  k0   : x fp32 -> xb bf16, per-parity channel sums (for mean of MixC)
//  k1   : MFMA GEMM xb @ [pin_h|pin_w]  -> p (bf16, window layouts)
//  k2   : MFMA GEMM per-head window mixing -> A_ext cols 512..543 + qsum
//  k3   : mean assembly -> reweight MLP -> softmax a0/a1/a2 (parallelized)
//  kd   : bias_vec[b][n] = proj_b + coef(b) @ proj_w
//  kf   : ext[b][n][32]  = (pout ∘ a) @ proj_w  (bf16)
//  k4   : v = MixC(x)*a2 -> A_ext cols 0..511 (bf16)
//  k5   : MFMA GEMM  out[65536,512] = A_ext[65536,544] @ [projT|ext_b] + bias
// ---------------------------------------------------------------------------

typedef short bf16x8 __attribute__((ext_vector_type(8)));
typedef float f32x4 __attribute__((ext_vector_type(4)));

__device__ __forceinline__ unsigned short f2bf(float f) {
  union { float f; unsigned u; } v; v.f = f;
  unsigned r = v.u + 0x7fffu + ((v.u >> 16) & 1u);
  return (unsigned short)(r >> 16);
}
__device__ __forceinline__ float bf2f(unsigned short h) {
  union { unsigned u; float f; } v; v.u = ((unsigned)h) << 16;
  return v.f;
}
__device__ __forceinline__ void gload16(const void* g, void* l) {
  __builtin_amdgcn_global_load_lds(
      (const __attribute__((address_space(1))) unsigned int*)g,
      (__attribute__((address_space(3))) unsigned int*)l, 16, 0, 0);
}

// ---------------- k_prep: small weight conversions + qsum zero -------------
__global__ __launch_bounds__(256) void k_prep(
    const float* __restrict__ mhfw, const float* __restrict__ mwfw,
    const float* __restrict__ mhpin, const float* __restrict__ mwpin,
    unsigned short* __restrict__ wfull, unsigned short* __restrict__ pin_bt,
    float* __restrict__ qsum) {
  int tid = blockIdx.x * 256 + threadIdx.x;
  int stride = gridDim.x * 256;
  for (int i = tid; i < 2 * 128 * 1024; i += stride) {
    int which = i >> 17, idx = i & 131071;
    wfull[i] = f2bf(which ? mwfw[idx] : mhfw[idx]);
  }
  for (int i = tid; i < 32 * 512; i += stride) {
    int n = i >> 9, k = i & 511;
    float v = (n < 16) ? mhpin[k * 16 + n] : mwpin[k * 16 + (n - 16)];
    pin_bt[i] = f2bf(v);
  }
  for (int i = tid; i < 512; i += stride) qsum[i] = 0.f;
}

// ---------------- kT: proj_w [512k,512n] -> projT bf16 [n][k] --------------
__global__ __launch_bounds__(256) void kT(const float* __restrict__ proj_w,
                                          unsigned short* __restrict__ projT) {
  __shared__ float t[64][65];
  int bx = blockIdx.x & 7, by = blockIdx.x >> 3;  // k-tile, n-tile
  int k0 = bx * 64, n0 = by * 64;
  int tid = threadIdx.x;
#pragma unroll
  for (int i = 0; i < 16; ++i) {
    int r = i * 4 + (tid >> 6), c = tid & 63;
    t[r][c] = proj_w[(size_t)(k0 + r) * 512 + n0 + c];
  }
  __syncthreads();
#pragma unroll
  for (int i = 0; i < 16; ++i) {
    int n = i * 4 + (tid >> 6), k = tid & 63;
    projT[(size_t)(n0 + n) * 512 + k0 + k] = f2bf(t[k][n]);
  }
}

// ---------------- k0: x -> bf16 + parity partial sums ----------------------
__global__ __launch_bounds__(256) void k0(const float* __restrict__ x,
                                          unsigned short* __restrict__ xb,
                                          float* __restrict__ part) {
  __shared__ float lds[2048];
  int blk = blockIdx.x;  // 256 blocks x 256 tokens
  int tid = threadIdx.x;
  int cq = tid & 127, rp = tid >> 7;
  int ch0 = cq * 4;
  size_t t0 = (size_t)blk * 256;
  float acc[2][4] = {};
#pragma unroll 4
  for (int it = 0; it < 128; ++it) {
    int tl = rp + 2 * it;
    size_t off = (t0 + tl) * 512 + ch0;
    float4 v = *(const float4*)&x[off];
    int dy = (tl >> 6) & 1;
    acc[dy][0] += v.x; acc[dy][1] += v.y; acc[dy][2] += v.z; acc[dy][3] += v.w;
    uint2 u;
    u.x = (unsigned)f2bf(v.x) | ((unsigned)f2bf(v.y) << 16);
    u.y = (unsigned)f2bf(v.z) | ((unsigned)f2bf(v.w) << 16);
    *(uint2*)&xb[off] = u;
  }
  for (int dy = 0; dy < 2; ++dy) {
    int d = dy * 2 + rp;  // (y parity)*2 + (x parity)
    for (int j = 0; j < 4; ++j) lds[d * 512 + ch0 + j] = acc[dy][j];
  }
  __syncthreads();
  for (int i = tid; i < 2048; i += 256) part[(size_t)blk * 2048 + i] = lds[i];
}

// ---------------- k1: proj_in GEMM [65536,512]@[512,32] --------------------
__global__ __launch_bounds__(256) void k1(
    const unsigned short* __restrict__ xb, const unsigned short* __restrict__ pin_bt,
    const float* __restrict__ mh_pin_b, const float* __restrict__ mw_pin_b,
    unsigned short* __restrict__ p_bf) {
  __shared__ unsigned short As[128 * 64];
  __shared__ unsigned short Bs[32 * 64];
  int mt = blockIdx.x;  // 512
  int tid = threadIdx.x, w = tid >> 6, l = tid & 63;
  int sr = l >> 3, sc = l & 7;
  f32x4 acc[2][2] = {};
  for (int kc = 0; kc < 8; ++kc) {  // K chunks of 64
#pragma unroll
    for (int c2 = 0; c2 < 4; ++c2) {
      int call = w * 4 + c2;
      int row = call * 8 + sr;
      gload16(xb + (size_t)(mt * 128 + row) * 512 + kc * 64 + sc * 8, &As[call * 512]);
    }
    {
      int row = w * 8 + sr;
      gload16(pin_bt + (size_t)row * 512 + kc * 64 + sc * 8, &Bs[w * 512]);
    }
    __syncthreads();
    bf16x8 af[2][2], bq[2][2];
#pragma unroll
    for (int fr = 0; fr < 2; ++fr) {
      int row = w * 32 + fr * 16 + (l & 15);
#pragma unroll
      for (int ks = 0; ks < 2; ++ks)
        af[fr][ks] = *(const bf16x8*)&As[row * 64 + ks * 32 + (l >> 4) * 8];
    }
#pragma unroll
    for (int fc = 0; fc < 2; ++fc) {
      int col = fc * 16 + (l & 15);
#pragma unroll
      for (int ks = 0; ks < 2; ++ks)
        bq[fc][ks] = *(const bf16x8*)&Bs[col * 64 + ks * 32 + (l >> 4) * 8];
    }
#pragma unroll
    for (int ks = 0; ks < 2; ++ks)
#pragma unroll
      for (int fr = 0; fr < 2; ++fr)
#pragma unroll
        for (int fc = 0; fc < 2; ++fc)
          acc[fr][fc] = __builtin_amdgcn_mfma_f32_16x16x32_bf16(
              af[fr][ks], bq[fc][ks], acc[fr][fc], 0, 0, 0);
    __syncthreads();
  }
  // epilogue: scatter p into window layouts (bf16)
#pragma unroll
  for (int fc = 0; fc < 2; ++fc) {
    int col = fc * 16 + (l & 15);
    float pb = (col < 16) ? mh_pin_b[col] : mw_pin_b[col - 16];
    int dd = col & 1;
    int whichm = (col < 16) ? (col >> 1) : (8 + ((col - 16) >> 1));
#pragma unroll
    for (int fr = 0; fr < 2; ++fr)
#pragma unroll
      for (int r = 0; r < 4; ++r) {
        int t = mt * 128 + w * 32 + fr * 16 + (l >> 4) * 4 + r;
        float val = acc[fr][fc][r] + pb;
        int bb = t >> 12, y = (t >> 6) & 63, xc = t & 63;
        int n1 = y & 1, ii = y >> 1, n2 = xc & 1, jj = xc >> 1;
        int b4 = bb * 4 + n1 * 2 + n2;
        int win, f;
        if (col < 16) { win = b4 * 16 + (jj >> 1); f = ii * 4 + (jj & 1) * 2 + dd; }
        else          { win = b4 * 16 + (ii >> 1); f = (ii & 1) * 64 + jj * 2 + dd; }
        p_bf[((size_t)whichm * 1024 + win) * 128 + f] = f2bf(val);
      }
  }
}

// ---------------- k2: per-head window mixing GEMM --------------------------
__global__ __launch_bounds__(256) void k2(
    const unsigned short* __restrict__ p_bf, const unsigned short* __restrict__ wfull,
    const float* __restrict__ mh_full_b, const float* __restrict__ mw_full_b,
    unsigned short* __restrict__ A_ext, float* __restrict__ qsum) {
  __shared__ unsigned short As[128 * 32];
  __shared__ unsigned short Bs[128 * 32];
  int bid = blockIdx.x;  // 128 = 2 which * 8 m * 8 mt
  int which = bid >> 6, m = (bid >> 3) & 7, mt = bid & 7;
  int tid = threadIdx.x, w = tid >> 6, l = tid & 63;
  int wr = w >> 1, wc = w & 1;
  const unsigned short* A = p_bf + (size_t)(which * 8 + m) * 131072;
  const unsigned short* BTw = wfull + (size_t)which * 131072 + m * 128;
  int win0 = mt * 128;
  f32x4 acc[4][4] = {};
  int sr = l >> 2, sc = l & 3;
  for (int kc = 0; kc < 4; ++kc) {
#pragma unroll
    for (int c2 = 0; c2 < 2; ++c2) {
      int call = w * 2 + c2;
      int row = call * 16 + sr;
      gload16(A + (size_t)(win0 + row) * 128 + kc * 32 + sc * 8, &As[call * 512]);
      gload16(BTw + (size_t)row * 1024 + kc * 32 + sc * 8, &Bs[call * 512]);
    }
    __syncthreads();
    bf16x8 af[4], bq[4];
#pragma unroll
    for (int fr = 0; fr < 4; ++fr)
      af[fr] = *(const bf16x8*)&As[(wr * 64 + fr * 16 + (l & 15)) * 32 + (l >> 4) * 8];
#pragma unroll
    for (int fc = 0; fc < 4; ++fc)
      bq[fc] = *(const bf16x8*)&Bs[(wc * 64 + fc * 16 + (l & 15)) * 32 + (l >> 4) * 8];
#pragma unroll
    for (int fr = 0; fr < 4; ++fr)
#pragma unroll
      for (int fc = 0; fc < 4; ++fc)
        acc[fr][fc] = __builtin_amdgcn_mfma_f32_16x16x32_bf16(af[fr], bq[fc], acc[fr][fc], 0, 0, 0);
    __syncthreads();
  }
  const float* fbp = which ? mw_full_b : mh_full_b;
  float psum = 0.f;
#pragma unroll
  for (int fc = 0; fc < 4; ++fc) {
    int f = wc * 64 + fc * 16 + (l & 15);
    float fb = fbp[f];
    int dd = f & 1;
#pragma unroll
    for (int fr = 0; fr < 4; ++fr)
#pragma unroll
      for (int r = 0; r < 4; ++r) {
        int win = win0 + wr * 64 + fr * 16 + (l >> 4) * 4 + r;
        float q = acc[fr][fc][r] + fb;
        psum += q;
        int b4 = win >> 4, loc = win & 15;
        int n1 = (b4 >> 1) & 1, n2 = b4 & 1, bb = b4 >> 2;
        int i_, j_;
        if (which == 0) { i_ = f >> 2;              j_ = loc * 2 + ((f >> 1) & 1); }
        else            { i_ = loc * 2 + (f >> 6);  j_ = (f >> 1) & 31; }
        int y = i_ * 2 + n1, xc = j_ * 2 + n2;
        size_t t = (size_t)bb * 4096 + y * 64 + xc;
        A_ext[t * 544 + 512 + which * 16 + m * 2 + dd] = f2bf(q);
      }
  }
  for (int off = 2; off < 64; off <<= 1) psum += __shfl_xor(psum, off);
  if (l < 2) atomicAdd(&qsum[(mt * 2 + wr) * 32 + which * 16 + m * 2 + l], psum);
}

// ---------------- k3: mean assembly + reweight MLP + softmax ---------------
__global__ __launch_bounds__(256) void k3(
    const float* __restrict__ part, const float* __restrict__ qsum,
    const float* __restrict__ cw, const float* __restrict__ cb,
    const float* __restrict__ mh_pout_w, const float* __restrict__ mh_pout_b,
    const float* __restrict__ mw_pout_w, const float* __restrict__ mw_pout_b,
    const float* __restrict__ fc1w, const float* __restrict__ fc1b,
    const float* __restrict__ fc2w, const float* __restrict__ fc2b,
    float* __restrict__ a_w) {
  __shared__ float apre[512];
  __shared__ float zpart[2][128];
  __shared__ float zz[128];
  __shared__ float lg[1536];
  int b = blockIdx.x, tid = threadIdx.x;
  float qh[16], qw[16];
#pragma unroll
  for (int k = 0; k < 16; ++k) {
    qh[k] = qsum[b * 32 + k] * (1.f / 4096.f);
    qw[k] = qsum[b * 32 + 16 + k] * (1.f / 4096.f);
  }
  for (int ch = tid; ch < 512; ch += 256) {
    float sd[4] = {0.f, 0.f, 0.f, 0.f};
    for (int i = 0; i < 16; ++i) {
      const float* pp = part + (size_t)(b * 16 + i) * 2048 + ch;
      sd[0] += pp[0]; sd[1] += pp[512]; sd[2] += pp[1024]; sd[3] += pp[1536];
    }
    float mc = 0.f;
#pragma unroll
    for (int d = 0; d < 4; ++d) {
      float wsum = cw[ch * 16 + d * 4] + cw[ch * 16 + d * 4 + 1] +
                   cw[ch * 16 + d * 4 + 2] + cw[ch * 16 + d * 4 + 3];
      mc += sd[d] * wsum;
    }
    mc *= (1.f / 4096.f);
    mc += 0.25f * (cb[ch * 4] + cb[ch * 4 + 1] + cb[ch * 4 + 2] + cb[ch * 4 + 3]);
    float v = mc + mh_pout_b[ch] + mw_pout_b[ch];
#pragma unroll
    for (int k = 0; k < 16; ++k)
      v += qh[k] * mh_pout_w[k * 512 + ch] + qw[k] * mw_pout_w[k * 512 + ch];
    apre[ch] = v;
  }
  __syncthreads();
  // fc1: 2-way K split, coalesced fc1w reads
  {
    int j = tid & 127, half = tid >> 7;
    float s = 0.f;
    for (int cc = 0; cc < 256; ++cc) {
      int c = half * 256 + cc;
      s += apre[c] * fc1w[c * 128 + j];
    }
    zpart[half][j] = s;
  }
  __syncthreads();
  if (tid < 128) {
    float s = fc1b[tid] + zpart[0][tid] + zpart[1][tid];
    zz[tid] = 0.5f * s * (1.f + erff(s * 0.70710678118654752f));
  }
  __syncthreads();
  // fc2 logits: coalesced over idx = ch*3+l
  for (int idx = tid; idx < 1536; idx += 256) {
    float s = fc2b[idx];
    for (int j = 0; j < 128; ++j) s += zz[j] * fc2w[j * 1536 + idx];
    lg[idx] = s;
  }
  __syncthreads();
  for (int ch = tid; ch < 512; ch += 256) {
    float l0 = lg[ch * 3], l1 = lg[ch * 3 + 1], l2 = lg[ch * 3 + 2];
    float mx = fmaxf(l0, fmaxf(l1, l2));
    float e0 = expf(l0 - mx), e1 = expf(l1 - mx), e2 = expf(l2 - mx);
    float inv = 1.f / (e0 + e1 + e2);
    a_w[b * 512 + ch] = e0 * inv;
    a_w[8192 + b * 512 + ch] = e1 * inv;
    a_w[16384 + b * 512 + ch] = e2 * inv;
  }
}

// ---------------- kd: bias_vec[b][n] -------------------------------------
__global__ __launch_bounds__(256) void kd(
    const float* __restrict__ a_w, const float* __restrict__ mh_pout_b,
    const float* __restrict__ mw_pout_b, const float* __restrict__ proj_w,
    const float* __restrict__ proj_b, float* __restrict__ bias_v) {
  __shared__ float coef[512];
  __shared__ float red[4][64];
  int b = blockIdx.x >> 3, nc = blockIdx.x & 7;
  int tid = threadIdx.x;
  for (int c = tid; c < 512; c += 256)
    coef[c] = mh_pout_b[c] * a_w[b * 512 + c] + mw_pout_b[c] * a_w[8192 + b * 512 + c];
  __syncthreads();
  int n = nc * 64 + (tid & 63), p4 = tid >> 6;
  float s = 0.f;
  for (int cc = 0; cc < 128; ++cc) {
    int c = p4 * 128 + cc;
    s += coef[c] * proj_w[(size_t)c * 512 + n];
  }
  red[p4][tid & 63] = s;
  __syncthreads();
  if (tid < 64) {
    bias_v[b * 512 + nc * 64 + tid] =
        proj_b[nc * 64 + tid] + red[0][tid] + red[1][tid] + red[2][tid] + red[3][tid];
  }
}

// ---------------- kf: ext[b][n][32] = (pout ∘ a) @ proj_w ------------------
__global__ __launch_bounds__(256) void kf(
    const float* __restrict__ a_w, const float* __restrict__ mh_pout_w,
    const float* __restrict__ mw_pout_w, const float* __restrict__ proj_w,
    unsigned short* __restrict__ ext) {
  __shared__ float pw0[32][512];  // 64 KiB
  int b = blockIdx.x >> 3, nc = blockIdx.x & 7;
  int tid = threadIdx.x;
  for (int i = tid; i < 32 * 512; i += 256) {
    int md = i >> 9, c = i & 511;
    float a = (md < 16) ? a_w[b * 512 + c] : a_w[8192 + b * 512 + c];
    float w = (md < 16) ? mh_pout_w[md * 512 + c] : mw_pout_w[(md - 16) * 512 + c];
    pw0[md][c] = a * w;
  }
  __syncthreads();
  int n = nc * 64 + (tid & 63), mq = tid >> 6;  // wave-uniform mq -> LDS broadcast
  float acc[8] = {};
  for (int c = 0; c < 512; ++c) {
    float pw = proj_w[(size_t)c * 512 + n];
#pragma unroll
    for (int j = 0; j < 8; ++j) acc[j] += pw * pw0[mq * 8 + j][c];
  }
  unsigned short o[8];
#pragma unroll
  for (int j = 0; j < 8; ++j) o[j] = f2bf(acc[j]);
  uint4 u;
  u.x = (unsigned)o[0] | ((unsigned)o[1] << 16);
  u.y = (unsigned)o[2] | ((unsigned)o[3] << 16);
  u.z = (unsigned)o[4] | ((unsigned)o[5] << 16);
  u.w = (unsigned)o[6] | ((unsigned)o[7] << 16);
  *(uint4*)&ext[((size_t)(b * 512 + n)) * 32 + mq * 8] = u;
}

// ---------------- k4: v = MixC(x) * a2 -> A_ext cols 0..511 ----------------
__global__ __launch_bounds__(256) void k4(const unsigned short* __restrict__ xb,
                                          const float* __restrict__ cw,
                                          const float* __restrict__ cb,
                                          const float* __restrict__ a_w,
                                          unsigned short* __restrict__ A_ext) {
  int blk = blockIdx.x;  // 512: 2 rows each
  int b = blk >> 5, y0 = (blk & 31) * 2;
  int tid = threadIdx.x;
  int ch0 = tid * 2;
  float wreg[2][16], breg[2][4], a2v[2];
#pragma unroll
  for (int cc = 0; cc < 2; ++cc) {
    int ch = ch0 + cc;
#pragma unroll
    for (int i = 0; i < 16; ++i) wreg[cc][i] = cw[ch * 16 + i];
#pragma unroll
    for (int i = 0; i < 4; ++i) breg[cc][i] = cb[ch * 4 + i];
    a2v[cc] = a_w[16384 + b * 512 + ch];
  }
  size_t rbase = ((size_t)b * 4096 + (size_t)y0 * 64) * 512;
  for (int j = 0; j < 32; ++j) {
    unsigned xw[4];
    xw[0] = *(const unsigned*)&xb[rbase + (size_t)(2 * j) * 512 + ch0];
    xw[1] = *(const unsigned*)&xb[rbase + (size_t)(2 * j + 1) * 512 + ch0];
    xw[2] = *(const unsigned*)&xb[rbase + 32768 + (size_t)(2 * j) * 512 + ch0];
    xw[3] = *(const unsigned*)&xb[rbase + 32768 + (size_t)(2 * j + 1) * 512 + ch0];
    float xv[4][2];
#pragma unroll
    for (int d = 0; d < 4; ++d) {
      xv[d][0] = bf2f((unsigned short)(xw[d] & 0xffffu));
      xv[d][1] = bf2f((unsigned short)(xw[d] >> 16));
    }
#pragma unroll
    for (int dh = 0; dh < 2; ++dh)
#pragma unroll
      for (int dw = 0; dw < 2; ++dw) {
        int Dp = dh * 2 + dw;
        unsigned short o2[2];
#pragma unroll
        for (int cc = 0; cc < 2; ++cc) {
          float v = breg[cc][Dp];
#pragma unroll
          for (int d = 0; d < 4; ++d) v += xv[d][cc] * wreg[cc][d * 4 + Dp];
          o2[cc] = f2bf(v * a2v[cc]);
        }
        size_t t = (size_t)b * 4096 + (size_t)(y0 + dh) * 64 + (2 * j + dw);
        *(unsigned*)&A_ext[t * 544 + ch0] = (unsigned)o2[0] | ((unsigned)o2[1] << 16);
      }
  }
}

// ---------------- k5: final GEMM [65536,544]@[544,512] + bias --------------
__global__ __launch_bounds__(256) void k5(const unsigned short* __restrict__ A_ext,
                                          const unsigned short* __restrict__ projT,
                                          const unsigned short* __restrict__ ext,
                                          const float* __restrict__ bias_vec,
                                          float* __restrict__ out) {
  __shared__ unsigned short As[128 * 32];
  __shared__ unsigned short Bs[128 * 32];
  int bid = blockIdx.x;
  int mt = bid >> 2, nt = bid & 3;
  int b = mt >> 5;
  int tid = threadIdx.x, w = tid >> 6, l = tid & 63;
  int wr = w >> 1, wc = w & 1;
  const unsigned short* Abase = A_ext + (size_t)(mt * 128) * 544;
  int n0 = nt * 128;
  f32x4 acc[4][4] = {};
  int sr = l >> 2, sc = l & 3;
  for (int kc = 0; kc < 17; ++kc) {
#pragma unroll
    for (int c2 = 0; c2 < 2; ++c2) {
      int call = w * 2 + c2;
      int row = call * 16 + sr;
      gload16(Abase + (size_t)row * 544 + kc * 32 + sc * 8, &As[call * 512]);
      if (kc < 16)
        gload16(projT + (size_t)(n0 + row) * 512 + kc * 32 + sc * 8, &Bs[call * 512]);
      else
        gload16(ext + ((size_t)(b * 512 + n0 + row)) * 32 + sc * 8, &Bs[call * 512]);
    }
    __syncthreads();
    bf16x8 af[4], bq[4];
#pragma unroll
    for (int fr = 0; fr < 4; ++fr)
      af[fr] = *(const bf16x8*)&As[(wr * 64 + fr * 16 + (l & 15)) * 32 + (l >> 4) * 8];
#pragma unroll
    for (int fc = 0; fc < 4; ++fc)
      bq[fc] = *(const bf16x8*)&Bs[(wc * 64 + fc * 16 + (l & 15)) * 32 + (l >> 4) * 8];
#pragma unroll
    for (int fr = 0; fr < 4; ++fr)
#pragma unroll
      for (int fc = 0; fc < 4; ++fc)
        acc[fr][fc] = __builtin_amdgcn_mfma_f32_16x16x32_bf16(af[fr], bq[fc], acc[fr][fc], 0, 0, 0);
    __syncthreads();
  }
  float bvals[4];
#pragma unroll
  for (int fc = 0; fc < 4; ++fc)
    bvals[fc] = bias_vec[b * 512 + nt * 128 + wc * 64 + fc * 16 + (l & 15)];
#pragma unroll
  for (int fr = 0; fr < 4; ++fr) {
    int row = mt * 128 + wr * 64 + fr * 16 + (l >> 4) * 4;
#pragma unroll
    for (int r = 0; r < 4; ++r) {
      size_t obase = (size_t)(row + r) * 512 + nt * 128 + wc * 64 + (l & 15);
#pragma unroll
      for (int fc = 0; fc < 4; ++fc) out[obase + fc * 16] = acc[fr][fc][r] + bvals[fc];
    }
  }
}

// ---------------------------------------------------------------------------
extern "C" void kernel_launch(void* const* d_in, const int* in_sizes, int n_in,
                              void* d_out, int out_size, void* d_ws, size_t ws_size,
                              hipStream_t stream) {
  const float* x         = (const float*)d_in[0];
  const float* mh_pin_w  = (const float*)d_in[1];
  const float* mh_pin_b  = (const float*)d_in[2];
  const float* mh_full_w = (const float*)d_in[3];
  const float* mh_full_b = (const float*)d_in[4];
  const float* mh_pout_w = (const float*)d_in[5];
  const float* mh_pout_b = (const float*)d_in[6];
  const float* mw_pin_w  = (const float*)d_in[7];
  const float* mw_pin_b  = (const float*)d_in[8];
  const float* mw_full_w = (const float*)d_in[9];
  const float* mw_full_b = (const float*)d_in[10];
  const float* mw_pout_w = (const float*)d_in[11];
  const float* mw_pout_b = (const float*)d_in[12];
  const float* cw        = (const float*)d_in[13];
  const float* cb        = (const float*)d_in[14];
  const float* fc1w      = (const float*)d_in[15];
  const float* fc1b      = (const float*)d_in[16];
  const float* fc2w      = (const float*)d_in[17];
  const float* fc2b      = (const float*)d_in[18];
  const float* proj_w    = (const float*)d_in[19];
  const float* proj_b    = (const float*)d_in[20];
  float* out = (float*)d_out;

  char* ws = (char*)d_ws;
  unsigned short* A_ext  = (unsigned short*)(ws + 0);            // 65536*544*2
  unsigned short* xb     = (unsigned short*)(ws + 71303168);     // 65536*512*2
  unsigned short* projT  = (unsigned short*)(ws + 138412032);    // 512*512*2
  unsigned short* ext    = (unsigned short*)(ws + 138936320);    // 16*512*32*2
  unsigned short* p_bf   = (unsigned short*)(ws + 147324928);    // 16*1024*128*2
  unsigned short* wfull  = (unsigned short*)(ws + 151519232);    // 2*128*1024*2
  unsigned short* pin_bt = (unsigned short*)(ws + 152043520);    // 32*512*2
  float* part    = (float*)(ws + 152076288);                     // 256*2048*4
  float* qsum    = (float*)(ws + 154173440);                     // 512*4
  float* a_wv    = (float*)(ws + 154175488);                     // 3*16*512*4
  float* bias_v  = (float*)(ws + 154273792);                     // 16*512*4

  k_prep<<<128, 256, 0, stream>>>(mh_full_w, mw_full_w, mh_pin_w, mw_pin_w, wfull, pin_bt, qsum);
  kT<<<64, 256, 0, stream>>>(proj_w, projT);
  k0<<<256, 256, 0, stream>>>(x, xb, part);
  k1<<<512, 256, 0, stream>>>(xb, pin_bt, mh_pin_b, mw_pin_b, p_bf);
  k2<<<128, 256, 0, stream>>>(p_bf, wfull, mh_full_b, mw_full_b, A_ext, qsum);
  k3<<<16, 256, 0, stream>>>(part, qsum, cw, cb, mh_pout_w, mh_pout_b, mw_pout_w, mw_pout_b,
                             fc1w, fc1b, fc2w, fc2b, a_wv);
  kd<<<128, 256, 0, stream>>>(a_wv, mh_pout_b, mw_pout_b, proj_w, proj_b, bias_v);
  kf<<<128, 256, 0, stream>>>(a_wv, mh_pout_w, mw_pout_w, proj_w, ext);
  k4<<<512, 256, 0, stream>>>(xb, cw, cb, a_wv, A_ext);
  k5<<<2048, 256, 0, stream>>>(A_ext, projT, ext, bias_v, out);
}

// Round 8
// 459.758 us; speedup vs baseline: 1.2787x; 1.1716x over previous
//
#include <hip/hip_runtime.h>

// ---------------------------------------------------------------------------
// TpMLPBlock on MI355X.
//  k_prep: convert full_w / pin^T to bf16, zero qsum
//  kT   : proj_w -> projT bf16 [n][k] (LDS transpose, shared across batch)
//  k0   : x fp32 -> xb bf16, per-parity channel sums (for mean of MixC)
//  k1   : MFMA GEMM xb @ [pin_h|pin_w]  -> p (bf16, window layouts)
//  k2   : MFMA GEMM per-head window mixing -> A_ext cols 512..543 + qsum
//  kA   : apre[b][512] assembly (128 blocks, i-split + LDS reduce)
//  kB   : fc1 partials zp[b][4][128] (64 blocks, K-split)
//  kD   : gelu + fc2 slice + softmax -> a_w (128 blocks)
//  kd   : bias_vec[b][n] = proj_b + coef(b) @ proj_w
//  kf   : ext[b][n][32]  = (pout ∘ a) @ proj_w  (bf16)
//  k4   : v = MixC(x)*a2 -> A_ext cols 0..511 (bf16)
//  k5   : MFMA GEMM  out[65536,512] = A_ext[65536,544] @ [projT|ext_b] + bias
// ---------------------------------------------------------------------------

typedef short bf16x8 __attribute__((ext_vector_type(8)));
typedef float f32x4 __attribute__((ext_vector_type(4)));

__device__ __forceinline__ unsigned short f2bf(float f) {
  union { float f; unsigned u; } v; v.f = f;
  unsigned r = v.u + 0x7fffu + ((v.u >> 16) & 1u);
  return (unsigned short)(r >> 16);
}
__device__ __forceinline__ float bf2f(unsigned short h) {
  union { unsigned u; float f; } v; v.u = ((unsigned)h) << 16;
  return v.f;
}
__device__ __forceinline__ void gload16(const void* g, void* l) {
  __builtin_amdgcn_global_load_lds(
      (const __attribute__((address_space(1))) unsigned int*)g,
      (__attribute__((address_space(3))) unsigned int*)l, 16, 0, 0);
}

// ---------------- k_prep: small weight conversions + qsum zero -------------
__global__ __launch_bounds__(256) void k_prep(
    const float* __restrict__ mhfw, const float* __restrict__ mwfw,
    const float* __restrict__ mhpin, const float* __restrict__ mwpin,
    unsigned short* __restrict__ wfull, unsigned short* __restrict__ pin_bt,
    float* __restrict__ qsum) {
  int tid = blockIdx.x * 256 + threadIdx.x;
  int stride = gridDim.x * 256;
  for (int i = tid; i < 2 * 128 * 1024; i += stride) {
    int which = i >> 17, idx = i & 131071;
    wfull[i] = f2bf(which ? mwfw[idx] : mhfw[idx]);
  }
  for (int i = tid; i < 32 * 512; i += stride) {
    int n = i >> 9, k = i & 511;
    float v = (n < 16) ? mhpin[k * 16 + n] : mwpin[k * 16 + (n - 16)];
    pin_bt[i] = f2bf(v);
  }
  for (int i = tid; i < 512; i += stride) qsum[i] = 0.f;
}

// ---------------- kT: proj_w [512k,512n] -> projT bf16 [n][k] --------------
__global__ __launch_bounds__(256) void kT(const float* __restrict__ proj_w,
                                          unsigned short* __restrict__ projT) {
  __shared__ float t[64][65];
  int bx = blockIdx.x & 7, by = blockIdx.x >> 3;  // k-tile, n-tile
  int k0 = bx * 64, n0 = by * 64;
  int tid = threadIdx.x;
#pragma unroll
  for (int i = 0; i < 16; ++i) {
    int r = i * 4 + (tid >> 6), c = tid & 63;
    t[r][c] = proj_w[(size_t)(k0 + r) * 512 + n0 + c];
  }
  __syncthreads();
#pragma unroll
  for (int i = 0; i < 16; ++i) {
    int n = i * 4 + (tid >> 6), k = tid & 63;
    projT[(size_t)(n0 + n) * 512 + k0 + k] = f2bf(t[k][n]);
  }
}

// ---------------- k0: x -> bf16 + parity partial sums ----------------------
__global__ __launch_bounds__(256) void k0(const float* __restrict__ x,
                                          unsigned short* __restrict__ xb,
                                          float* __restrict__ part) {
  __shared__ float lds[2048];
  int blk = blockIdx.x;  // 256 blocks x 256 tokens
  int tid = threadIdx.x;
  int cq = tid & 127, rp = tid >> 7;
  int ch0 = cq * 4;
  size_t t0 = (size_t)blk * 256;
  float acc[2][4] = {};
#pragma unroll 4
  for (int it = 0; it < 128; ++it) {
    int tl = rp + 2 * it;
    size_t off = (t0 + tl) * 512 + ch0;
    float4 v = *(const float4*)&x[off];
    int dy = (tl >> 6) & 1;
    acc[dy][0] += v.x; acc[dy][1] += v.y; acc[dy][2] += v.z; acc[dy][3] += v.w;
    uint2 u;
    u.x = (unsigned)f2bf(v.x) | ((unsigned)f2bf(v.y) << 16);
    u.y = (unsigned)f2bf(v.z) | ((unsigned)f2bf(v.w) << 16);
    *(uint2*)&xb[off] = u;
  }
  for (int dy = 0; dy < 2; ++dy) {
    int d = dy * 2 + rp;  // (y parity)*2 + (x parity)
    for (int j = 0; j < 4; ++j) lds[d * 512 + ch0 + j] = acc[dy][j];
  }
  __syncthreads();
  for (int i = tid; i < 2048; i += 256) part[(size_t)blk * 2048 + i] = lds[i];
}

// ---------------- k1: proj_in GEMM [65536,512]@[512,32] --------------------
__global__ __launch_bounds__(256) void k1(
    const unsigned short* __restrict__ xb, const unsigned short* __restrict__ pin_bt,
    const float* __restrict__ mh_pin_b, const float* __restrict__ mw_pin_b,
    unsigned short* __restrict__ p_bf) {
  __shared__ unsigned short As[128 * 64];
  __shared__ unsigned short Bs[32 * 64];
  int mt = blockIdx.x;  // 512
  int tid = threadIdx.x, w = tid >> 6, l = tid & 63;
  int sr = l >> 3, sc = l & 7;
  f32x4 acc[2][2] = {};
  for (int kc = 0; kc < 8; ++kc) {  // K chunks of 64
#pragma unroll
    for (int c2 = 0; c2 < 4; ++c2) {
      int call = w * 4 + c2;
      int row = call * 8 + sr;
      gload16(xb + (size_t)(mt * 128 + row) * 512 + kc * 64 + sc * 8, &As[call * 512]);
    }
    {
      int row = w * 8 + sr;
      gload16(pin_bt + (size_t)row * 512 + kc * 64 + sc * 8, &Bs[w * 512]);
    }
    __syncthreads();
    bf16x8 af[2][2], bq[2][2];
#pragma unroll
    for (int fr = 0; fr < 2; ++fr) {
      int row = w * 32 + fr * 16 + (l & 15);
#pragma unroll
      for (int ks = 0; ks < 2; ++ks)
        af[fr][ks] = *(const bf16x8*)&As[row * 64 + ks * 32 + (l >> 4) * 8];
    }
#pragma unroll
    for (int fc = 0; fc < 2; ++fc) {
      int col = fc * 16 + (l & 15);
#pragma unroll
      for (int ks = 0; ks < 2; ++ks)
        bq[fc][ks] = *(const bf16x8*)&Bs[col * 64 + ks * 32 + (l >> 4) * 8];
    }
#pragma unroll
    for (int ks = 0; ks < 2; ++ks)
#pragma unroll
      for (int fr = 0; fr < 2; ++fr)
#pragma unroll
        for (int fc = 0; fc < 2; ++fc)
          acc[fr][fc] = __builtin_amdgcn_mfma_f32_16x16x32_bf16(
              af[fr][ks], bq[fc][ks], acc[fr][fc], 0, 0, 0);
    __syncthreads();
  }
  // epilogue: scatter p into window layouts (bf16)
#pragma unroll
  for (int fc = 0; fc < 2; ++fc) {
    int col = fc * 16 + (l & 15);
    float pb = (col < 16) ? mh_pin_b[col] : mw_pin_b[col - 16];
    int dd = col & 1;
    int whichm = (col < 16) ? (col >> 1) : (8 + ((col - 16) >> 1));
#pragma unroll
    for (int fr = 0; fr < 2; ++fr)
#pragma unroll
      for (int r = 0; r < 4; ++r) {
        int t = mt * 128 + w * 32 + fr * 16 + (l >> 4) * 4 + r;
        float val = acc[fr][fc][r] + pb;
        int bb = t >> 12, y = (t >> 6) & 63, xc = t & 63;
        int n1 = y & 1, ii = y >> 1, n2 = xc & 1, jj = xc >> 1;
        int b4 = bb * 4 + n1 * 2 + n2;
        int win, f;
        if (col < 16) { win = b4 * 16 + (jj >> 1); f = ii * 4 + (jj & 1) * 2 + dd; }
        else          { win = b4 * 16 + (ii >> 1); f = (ii & 1) * 64 + jj * 2 + dd; }
        p_bf[((size_t)whichm * 1024 + win) * 128 + f] = f2bf(val);
      }
  }
}

// ---------------- k2: per-head window mixing GEMM --------------------------
__global__ __launch_bounds__(256) void k2(
    const unsigned short* __restrict__ p_bf, const unsigned short* __restrict__ wfull,
    const float* __restrict__ mh_full_b, const float* __restrict__ mw_full_b,
    unsigned short* __restrict__ A_ext, float* __restrict__ qsum) {
  __shared__ unsigned short As[128 * 32];
  __shared__ unsigned short Bs[128 * 32];
  int bid = blockIdx.x;  // 128 = 2 which * 8 m * 8 mt
  int which = bid >> 6, m = (bid >> 3) & 7, mt = bid & 7;
  int tid = threadIdx.x, w = tid >> 6, l = tid & 63;
  int wr = w >> 1, wc = w & 1;
  const unsigned short* A = p_bf + (size_t)(which * 8 + m) * 131072;
  const unsigned short* BTw = wfull + (size_t)which * 131072 + m * 128;
  int win0 = mt * 128;
  f32x4 acc[4][4] = {};
  int sr = l >> 2, sc = l & 3;
  for (int kc = 0; kc < 4; ++kc) {
#pragma unroll
    for (int c2 = 0; c2 < 2; ++c2) {
      int call = w * 2 + c2;
      int row = call * 16 + sr;
      gload16(A + (size_t)(win0 + row) * 128 + kc * 32 + sc * 8, &As[call * 512]);
      gload16(BTw + (size_t)row * 1024 + kc * 32 + sc * 8, &Bs[call * 512]);
    }
    __syncthreads();
    bf16x8 af[4], bq[4];
#pragma unroll
    for (int fr = 0; fr < 4; ++fr)
      af[fr] = *(const bf16x8*)&As[(wr * 64 + fr * 16 + (l & 15)) * 32 + (l >> 4) * 8];
#pragma unroll
    for (int fc = 0; fc < 4; ++fc)
      bq[fc] = *(const bf16x8*)&Bs[(wc * 64 + fc * 16 + (l & 15)) * 32 + (l >> 4) * 8];
#pragma unroll
    for (int fr = 0; fr < 4; ++fr)
#pragma unroll
      for (int fc = 0; fc < 4; ++fc)
        acc[fr][fc] = __builtin_amdgcn_mfma_f32_16x16x32_bf16(af[fr], bq[fc], acc[fr][fc], 0, 0, 0);
    __syncthreads();
  }
  const float* fbp = which ? mw_full_b : mh_full_b;
  float psum = 0.f;
#pragma unroll
  for (int fc = 0; fc < 4; ++fc) {
    int f = wc * 64 + fc * 16 + (l & 15);
    float fb = fbp[f];
    int dd = f & 1;
#pragma unroll
    for (int fr = 0; fr < 4; ++fr)
#pragma unroll
      for (int r = 0; r < 4; ++r) {
        int win = win0 + wr * 64 + fr * 16 + (l >> 4) * 4 + r;
        float q = acc[fr][fc][r] + fb;
        psum += q;
        int b4 = win >> 4, loc = win & 15;
        int n1 = (b4 >> 1) & 1, n2 = b4 & 1, bb = b4 >> 2;
        int i_, j_;
        if (which == 0) { i_ = f >> 2;              j_ = loc * 2 + ((f >> 1) & 1); }
        else            { i_ = loc * 2 + (f >> 6);  j_ = (f >> 1) & 31; }
        int y = i_ * 2 + n1, xc = j_ * 2 + n2;
        size_t t = (size_t)bb * 4096 + y * 64 + xc;
        A_ext[t * 544 + 512 + which * 16 + m * 2 + dd] = f2bf(q);
      }
  }
  for (int off = 2; off < 64; off <<= 1) psum += __shfl_xor(psum, off);
  if (l < 2) atomicAdd(&qsum[(mt * 2 + wr) * 32 + which * 16 + m * 2 + l], psum);
}

// ---------------- kA: apre[b][512] assembly (16b x 8chunk blocks) ----------
__global__ __launch_bounds__(256) void kA(
    const float* __restrict__ part, const float* __restrict__ qsum,
    const float* __restrict__ cw, const float* __restrict__ cb,
    const float* __restrict__ mh_pout_w, const float* __restrict__ mh_pout_b,
    const float* __restrict__ mw_pout_w, const float* __restrict__ mw_pout_b,
    float* __restrict__ apre_g) {
  __shared__ float red[4][4][64];
  int b = blockIdx.x >> 3, chunk = blockIdx.x & 7;
  int tid = threadIdx.x;
  int lc = tid & 63, p4 = tid >> 6;
  int ch = chunk * 64 + lc;
  float sd[4] = {0.f, 0.f, 0.f, 0.f};
#pragma unroll
  for (int ii = 0; ii < 4; ++ii) {
    int i = p4 * 4 + ii;
    const float* pp = part + (size_t)(b * 16 + i) * 2048 + ch;
    sd[0] += pp[0]; sd[1] += pp[512]; sd[2] += pp[1024]; sd[3] += pp[1536];
  }
#pragma unroll
  for (int d = 0; d < 4; ++d) red[p4][d][lc] = sd[d];
  __syncthreads();
  if (p4 == 0) {
    float mc = 0.f;
#pragma unroll
    for (int d = 0; d < 4; ++d) {
      float sfull = red[0][d][lc] + red[1][d][lc] + red[2][d][lc] + red[3][d][lc];
      float wsum = cw[ch * 16 + d * 4] + cw[ch * 16 + d * 4 + 1] +
                   cw[ch * 16 + d * 4 + 2] + cw[ch * 16 + d * 4 + 3];
      mc += sfull * wsum;
    }
    mc *= (1.f / 4096.f);
    mc += 0.25f * (cb[ch * 4] + cb[ch * 4 + 1] + cb[ch * 4 + 2] + cb[ch * 4 + 3]);
    float v = mc + mh_pout_b[ch] + mw_pout_b[ch];
#pragma unroll
    for (int k = 0; k < 16; ++k) {
      float qh = qsum[b * 32 + k] * (1.f / 4096.f);
      float qw = qsum[b * 32 + 16 + k] * (1.f / 4096.f);
      v += qh * mh_pout_w[k * 512 + ch] + qw * mw_pout_w[k * 512 + ch];
    }
    apre_g[b * 512 + ch] = v;
  }
}

// ---------------- kB: fc1 partials zp[b][4][128] (16b x 4ks blocks) --------
__global__ __launch_bounds__(256) void kB(
    const float* __restrict__ apre_g, const float* __restrict__ fc1w,
    float* __restrict__ zp) {
  __shared__ float red[2][128];
  int b = blockIdx.x >> 2, ks = blockIdx.x & 3;
  int tid = threadIdx.x;
  int j = tid & 127, half = tid >> 7;
  float s = 0.f;
#pragma unroll 8
  for (int cc = 0; cc < 64; ++cc) {
    int c = ks * 128 + half * 64 + cc;
    s += apre_g[b * 512 + c] * fc1w[c * 128 + j];
  }
  red[half][j] = s;
  __syncthreads();
  if (tid < 128) zp[(b * 4 + ks) * 128 + tid] = red[0][tid] + red[1][tid];
}

// ---------------- kD: gelu + fc2 slice + softmax (16b x 8chunk) ------------
__global__ __launch_bounds__(256) void kD(
    const float* __restrict__ zp, const float* __restrict__ fc1b,
    const float* __restrict__ fc2w, const float* __restrict__ fc2b,
    float* __restrict__ a_w) {
  __shared__ float zz[128];
  __shared__ float lg[192];
  int b = blockIdx.x >> 3, chunk = blockIdx.x & 7;
  int tid = threadIdx.x;
  if (tid < 128) {
    float s = fc1b[tid] + zp[(b * 4 + 0) * 128 + tid] + zp[(b * 4 + 1) * 128 + tid] +
              zp[(b * 4 + 2) * 128 + tid] + zp[(b * 4 + 3) * 128 + tid];
    zz[tid] = 0.5f * s * (1.f + erff(s * 0.70710678118654752f));
  }
  __syncthreads();
  if (tid < 192) {
    int col = chunk * 192 + tid;
    float s = fc2b[col];
#pragma unroll 8
    for (int j = 0; j < 128; ++j) s += zz[j] * fc2w[j * 1536 + col];
    lg[tid] = s;
  }
  __syncthreads();
  if (tid < 64) {
    int ch = chunk * 64 + tid;
    float l0 = lg[tid * 3], l1 = lg[tid * 3 + 1], l2 = lg[tid * 3 + 2];
    float mx = fmaxf(l0, fmaxf(l1, l2));
    float e0 = expf(l0 - mx), e1 = expf(l1 - mx), e2 = expf(l2 - mx);
    float inv = 1.f / (e0 + e1 + e2);
    a_w[b * 512 + ch] = e0 * inv;
    a_w[8192 + b * 512 + ch] = e1 * inv;
    a_w[16384 + b * 512 + ch] = e2 * inv;
  }
}

// ---------------- kd: bias_vec[b][n] -------------------------------------
__global__ __launch_bounds__(256) void kd(
    const float* __restrict__ a_w, const float* __restrict__ mh_pout_b,
    const float* __restrict__ mw_pout_b, const float* __restrict__ proj_w,
    const float* __restrict__ proj_b, float* __restrict__ bias_v) {
  __shared__ float coef[512];
  __shared__ float red[4][64];
  int b = blockIdx.x >> 3, nc = blockIdx.x & 7;
  int tid = threadIdx.x;
  for (int c = tid; c < 512; c += 256)
    coef[c] = mh_pout_b[c] * a_w[b * 512 + c] + mw_pout_b[c] * a_w[8192 + b * 512 + c];
  __syncthreads();
  int n = nc * 64 + (tid & 63), p4 = tid >> 6;
  float s = 0.f;
#pragma unroll 8
  for (int cc = 0; cc < 128; ++cc) {
    int c = p4 * 128 + cc;
    s += coef[c] * proj_w[(size_t)c * 512 + n];
  }
  red[p4][tid & 63] = s;
  __syncthreads();
  if (tid < 64) {
    bias_v[b * 512 + nc * 64 + tid] =
        proj_b[nc * 64 + tid] + red[0][tid] + red[1][tid] + red[2][tid] + red[3][tid];
  }
}

// ---------------- kf: ext[b][n][32] = (pout ∘ a) @ proj_w ------------------
__global__ __launch_bounds__(256) void kf(
    const float* __restrict__ a_w, const float* __restrict__ mh_pout_w,
    const float* __restrict__ mw_pout_w, const float* __restrict__ proj_w,
    unsigned short* __restrict__ ext) {
  __shared__ float pw0[32][512];  // 64 KiB
  int b = blockIdx.x >> 3, nc = blockIdx.x & 7;
  int tid = threadIdx.x;
  for (int i = tid; i < 32 * 512; i += 256) {
    int md = i >> 9, c = i & 511;
    float a = (md < 16) ? a_w[b * 512 + c] : a_w[8192 + b * 512 + c];
    float w = (md < 16) ? mh_pout_w[md * 512 + c] : mw_pout_w[(md - 16) * 512 + c];
    pw0[md][c] = a * w;
  }
  __syncthreads();
  int n = nc * 64 + (tid & 63), mq = tid >> 6;  // wave-uniform mq -> LDS broadcast
  float acc[8] = {};
#pragma unroll 4
  for (int c = 0; c < 512; ++c) {
    float pw = proj_w[(size_t)c * 512 + n];
#pragma unroll
    for (int j = 0; j < 8; ++j) acc[j] += pw * pw0[mq * 8 + j][c];
  }
  unsigned short o[8];
#pragma unroll
  for (int j = 0; j < 8; ++j) o[j] = f2bf(acc[j]);
  uint4 u;
  u.x = (unsigned)o[0] | ((unsigned)o[1] << 16);
  u.y = (unsigned)o[2] | ((unsigned)o[3] << 16);
  u.z = (unsigned)o[4] | ((unsigned)o[5] << 16);
  u.w = (unsigned)o[6] | ((unsigned)o[7] << 16);
  *(uint4*)&ext[((size_t)(b * 512 + n)) * 32 + mq * 8] = u;
}

// ---------------- k4: v = MixC(x) * a2 -> A_ext cols 0..511 ----------------
__global__ __launch_bounds__(256) void k4(const unsigned short* __restrict__ xb,
                                          const float* __restrict__ cw,
                                          const float* __restrict__ cb,
                                          const float* __restrict__ a_w,
                                          unsigned short* __restrict__ A_ext) {
  int blk = blockIdx.x;  // 512: 2 rows each
  int b = blk >> 5, y0 = (blk & 31) * 2;
  int tid = threadIdx.x;
  int ch0 = tid * 2;
  float wreg[2][16], breg[2][4], a2v[2];
#pragma unroll
  for (int cc = 0; cc < 2; ++cc) {
    int ch = ch0 + cc;
#pragma unroll
    for (int i = 0; i < 16; ++i) wreg[cc][i] = cw[ch * 16 + i];
#pragma unroll
    for (int i = 0; i < 4; ++i) breg[cc][i] = cb[ch * 4 + i];
    a2v[cc] = a_w[16384 + b * 512 + ch];
  }
  size_t rbase = ((size_t)b * 4096 + (size_t)y0 * 64) * 512;
  for (int j = 0; j < 32; ++j) {
    unsigned xw[4];
    xw[0] = *(const unsigned*)&xb[rbase + (size_t)(2 * j) * 512 + ch0];
    xw[1] = *(const unsigned*)&xb[rbase + (size_t)(2 * j + 1) * 512 + ch0];
    xw[2] = *(const unsigned*)&xb[rbase + 32768 + (size_t)(2 * j) * 512 + ch0];
    xw[3] = *(const unsigned*)&xb[rbase + 32768 + (size_t)(2 * j + 1) * 512 + ch0];
    float xv[4][2];
#pragma unroll
    for (int d = 0; d < 4; ++d) {
      xv[d][0] = bf2f((unsigned short)(xw[d] & 0xffffu));
      xv[d][1] = bf2f((unsigned short)(xw[d] >> 16));
    }
#pragma unroll
    for (int dh = 0; dh < 2; ++dh)
#pragma unroll
      for (int dw = 0; dw < 2; ++dw) {
        int Dp = dh * 2 + dw;
        unsigned short o2[2];
#pragma unroll
        for (int cc = 0; cc < 2; ++cc) {
          float v = breg[cc][Dp];
#pragma unroll
          for (int d = 0; d < 4; ++d) v += xv[d][cc] * wreg[cc][d * 4 + Dp];
          o2[cc] = f2bf(v * a2v[cc]);
        }
        size_t t = (size_t)b * 4096 + (size_t)(y0 + dh) * 64 + (2 * j + dw);
        *(unsigned*)&A_ext[t * 544 + ch0] = (unsigned)o2[0] | ((unsigned)o2[1] << 16);
      }
  }
}

// ---------------- k5: final GEMM [65536,544]@[544,512] + bias --------------
__global__ __launch_bounds__(256) void k5(const unsigned short* __restrict__ A_ext,
                                          const unsigned short* __restrict__ projT,
                                          const unsigned short* __restrict__ ext,
                                          const float* __restrict__ bias_vec,
                                          float* __restrict__ out) {
  __shared__ unsigned short As[128 * 32];
  __shared__ unsigned short Bs[128 * 32];
  int bid = blockIdx.x;
  int mt = bid >> 2, nt = bid & 3;
  int b = mt >> 5;
  int tid = threadIdx.x, w = tid >> 6, l = tid & 63;
  int wr = w >> 1, wc = w & 1;
  const unsigned short* Abase = A_ext + (size_t)(mt * 128) * 544;
  int n0 = nt * 128;
  f32x4 acc[4][4] = {};
  int sr = l >> 2, sc = l & 3;
  for (int kc = 0; kc < 17; ++kc) {
#pragma unroll
    for (int c2 = 0; c2 < 2; ++c2) {
      int call = w * 2 + c2;
      int row = call * 16 + sr;
      gload16(Abase + (size_t)row * 544 + kc * 32 + sc * 8, &As[call * 512]);
      if (kc < 16)
        gload16(projT + (size_t)(n0 + row) * 512 + kc * 32 + sc * 8, &Bs[call * 512]);
      else
        gload16(ext + ((size_t)(b * 512 + n0 + row)) * 32 + sc * 8, &Bs[call * 512]);
    }
    __syncthreads();
    bf16x8 af[4], bq[4];
#pragma unroll
    for (int fr = 0; fr < 4; ++fr)
      af[fr] = *(const bf16x8*)&As[(wr * 64 + fr * 16 + (l & 15)) * 32 + (l >> 4) * 8];
#pragma unroll
    for (int fc = 0; fc < 4; ++fc)
      bq[fc] = *(const bf16x8*)&Bs[(wc * 64 + fc * 16 + (l & 15)) * 32 + (l >> 4) * 8];
#pragma unroll
    for (int fr = 0; fr < 4; ++fr)
#pragma unroll
      for (int fc = 0; fc < 4; ++fc)
        acc[fr][fc] = __builtin_amdgcn_mfma_f32_16x16x32_bf16(af[fr], bq[fc], acc[fr][fc], 0, 0, 0);
    __syncthreads();
  }
  float bvals[4];
#pragma unroll
  for (int fc = 0; fc < 4; ++fc)
    bvals[fc] = bias_vec[b * 512 + nt * 128 + wc * 64 + fc * 16 + (l & 15)];
#pragma unroll
  for (int fr = 0; fr < 4; ++fr) {
    int row = mt * 128 + wr * 64 + fr * 16 + (l >> 4) * 4;
#pragma unroll
    for (int r = 0; r < 4; ++r) {
      size_t obase = (size_t)(row + r) * 512 + nt * 128 + wc * 64 + (l & 15);
#pragma unroll
      for (int fc = 0; fc < 4; ++fc) out[obase + fc * 16] = acc[fr][fc][r] + bvals[fc];
    }
  }
}

// ---------------------------------------------------------------------------
extern "C" void kernel_launch(void* const* d_in, const int* in_sizes, int n_in,
                              void* d_out, int out_size, void* d_ws, size_t ws_size,
                              hipStream_t stream) {
  const float* x         = (const float*)d_in[0];
  const float* mh_pin_w  = (const float*)d_in[1];
  const float* mh_pin_b  = (const float*)d_in[2];
  const float* mh_full_w = (const float*)d_in[3];
  const float* mh_full_b = (const float*)d_in[4];
  const float* mh_pout_w = (const float*)d_in[5];
  const float* mh_pout_b = (const float*)d_in[6];
  const float* mw_pin_w  = (const float*)d_in[7];
  const float* mw_pin_b  = (const float*)d_in[8];
  const float* mw_full_w = (const float*)d_in[9];
  const float* mw_full_b = (const float*)d_in[10];
  const float* mw_pout_w = (const float*)d_in[11];
  const float* mw_pout_b = (const float*)d_in[12];
  const float* cw        = (const float*)d_in[13];
  const float* cb        = (const float*)d_in[14];
  const float* fc1w      = (const float*)d_in[15];
  const float* fc1b      = (const float*)d_in[16];
  const float* fc2w      = (const float*)d_in[17];
  const float* fc2b      = (const float*)d_in[18];
  const float* proj_w    = (const float*)d_in[19];
  const float* proj_b    = (const float*)d_in[20];
  float* out = (float*)d_out;

  char* ws = (char*)d_ws;
  unsigned short* A_ext  = (unsigned short*)(ws + 0);            // 65536*544*2
  unsigned short* xb     = (unsigned short*)(ws + 71303168);     // 65536*512*2
  unsigned short* projT  = (unsigned short*)(ws + 138412032);    // 512*512*2
  unsigned short* ext    = (unsigned short*)(ws + 138936320);    // 16*512*32*2
  unsigned short* p_bf   = (unsigned short*)(ws + 147324928);    // 16*1024*128*2
  unsigned short* wfull  = (unsigned short*)(ws + 151519232);    // 2*128*1024*2
  unsigned short* pin_bt = (unsigned short*)(ws + 152043520);    // 32*512*2
  float* part    = (float*)(ws + 152076288);                     // 256*2048*4
  float* qsum    = (float*)(ws + 154173440);                     // 512*4
  float* a_wv    = (float*)(ws + 154175488);                     // 3*16*512*4
  float* bias_v  = (float*)(ws + 154273792);                     // 16*512*4
  // reuse dead p_bf region (k1/k2 done before kA/kB run)
  float* apre_g  = (float*)(ws + 147324928);                     // 16*512*4 = 32 KB
  float* zp      = (float*)(ws + 147324928 + 32768);             // 16*4*128*4 = 32 KB

  k_prep<<<128, 256, 0, stream>>>(mh_full_w, mw_full_w, mh_pin_w, mw_pin_w, wfull, pin_bt, qsum);
  kT<<<64, 256, 0, stream>>>(proj_w, projT);
  k0<<<256, 256, 0, stream>>>(x, xb, part);
  k1<<<512, 256, 0, stream>>>(xb, pin_bt, mh_pin_b, mw_pin_b, p_bf);
  k2<<<128, 256, 0, stream>>>(p_bf, wfull, mh_full_b, mw_full_b, A_ext, qsum);
  kA<<<128, 256, 0, stream>>>(part, qsum, cw, cb, mh_pout_w, mh_pout_b, mw_pout_w, mw_pout_b,
                              apre_g);
  kB<<<64, 256, 0, stream>>>(apre_g, fc1w, zp);
  kD<<<128, 256, 0, stream>>>(zp, fc1b, fc2w, fc2b, a_wv);
  kd<<<128, 256, 0, stream>>>(a_wv, mh_pout_b, mw_pout_b, proj_w, proj_b, bias_v);
  kf<<<128, 256, 0, stream>>>(a_wv, mh_pout_w, mw_pout_w, proj_w, ext);
  k4<<<512, 256, 0, stream>>>(xb, cw, cb, a_wv, A_ext);
  k5<<<2048, 256, 0, stream>>>(A_ext, projT, ext, bias_v, out);
}